// Round 3
// baseline (171.558 us; speedup 1.0000x reference)
//
#include <hip/hip_runtime.h>

#define NCLS 80
#define REC  255            // 3*85 floats per (b,cell) record in ytrue
#define NA   3
#define BSZ  16
#define MAXB 32

#define G0 13
#define G1 26
#define G2 52
#define GG0 (G0*G0)
#define GG1 (G1*G1)
#define GG2 (G2*G2)
#define CELLS0 (BSZ*NA*GG0)
#define CELLS1 (BSZ*NA*GG1)
#define CELLS2 (BSZ*NA*GG2)
#define TOTAL  (CELLS0+CELLS1+CELLS2)     // 170352

#define MB ((TOTAL+255)/256)   // 666 main blocks
#define OB 240                 // obj-correction blocks: 4 waves each -> 960 slots

__device__ const float d_anch[3][3][2] = {
  {{116.f, 90.f}, {156.f, 198.f}, {373.f, 326.f}},
  {{ 30.f, 61.f}, { 62.f,  45.f}, { 59.f, 119.f}},
  {{ 10.f, 13.f}, { 16.f,  30.f}, { 33.f,  23.f}},
};

__device__ inline float sp(float x) {          // softplus, stable
  return fmaxf(x, 0.0f) + log1pf(expf(-fabsf(x)));
}
__device__ inline float sigm(float x) { return 1.0f / (1.0f + expf(-x)); }
__device__ inline float wred(float v) {
  #pragma unroll
  for (int off = 32; off > 0; off >>= 1) v += __shfl_down(v, off, 64);
  return v;
}
__device__ inline float wmax(float v) {
  #pragma unroll
  for (int off = 32; off > 0; off >>= 1) v = fmaxf(v, __shfl_xor(v, off, 64));
  return v;
}

// grp (= l*16+b) of a global cell index; all divisors compile-time constants
__device__ inline int cell_grp(int t) {
  if (t < CELLS0) {
    unsigned r = (unsigned)t / (unsigned)GG0; return (int)(r / 3u);
  } else if (t < CELLS0 + CELLS1) {
    unsigned r = (unsigned)(t - CELLS0) / (unsigned)GG1; return 16 + (int)(r / 3u);
  }
  unsigned r = (unsigned)(t - CELLS0 - CELLS1) / (unsigned)GG2; return 32 + (int)(r / 3u);
}

// ------------- kernel 1: one thread per obj word (strided gather) -----------
template<int L>
__device__ inline void gather_one(int idx, const float* __restrict__ yt,
                                  int* __restrict__ cnt, float* __restrict__ boxes,
                                  int* __restrict__ total, int* __restrict__ objlist) {
  constexpr int GG = (L == 0) ? GG0 : (L == 1) ? GG1 : GG2;
  unsigned rest = (unsigned)idx / (unsigned)GG;       // const divisor
  int cell = idx - (int)rest * GG;
  unsigned b = rest / 3u;
  int a = (int)(rest - b * 3u);
  size_t base = ((size_t)((int)b * GG + cell) * 3 + a) * 85;
  float obj = yt[base + 4];
  if (obj > 0.5f) {
    int grp = L * BSZ + (int)b;
    int p = atomicAdd(&cnt[grp], 1);
    if (p < MAXB) {
      float* d = boxes + (grp * MAXB + p) * 4;
      d[0] = yt[base]; d[1] = yt[base + 1]; d[2] = yt[base + 2]; d[3] = yt[base + 3];
    }
    int s = atomicAdd(total, 1);
    if (s < 1024) objlist[s] = (grp << 18) | (a << 16) | cell;
  }
}

__global__ __launch_bounds__(256)
void gather_kernel(const float* __restrict__ y0, const float* __restrict__ y1,
                   const float* __restrict__ y2, int* __restrict__ cnt,
                   float* __restrict__ boxes, int* __restrict__ total,
                   int* __restrict__ objlist) {
  int t = blockIdx.x * 256 + threadIdx.x;
  if (t >= TOTAL) return;
  if (t < CELLS0)               gather_one<0>(t,                   y0, cnt, boxes, total, objlist);
  else if (t < CELLS0 + CELLS1) gather_one<1>(t - CELLS0,          y1, cnt, boxes, total, objlist);
  else                          gather_one<2>(t - CELLS0 - CELLS1, y2, cnt, boxes, total, objlist);
}

// ------------- kernel 2: losses + finalize ----------------------------------
template<int L>
__device__ inline float conf_cell(int idx, const float* __restrict__ fp,
                                  const float4* __restrict__ sbox,
                                  const int* __restrict__ scnt, int gmin) {
  constexpr int GG = (L == 0) ? GG0 : (L == 1) ? GG1 : GG2;
  constexpr int G  = (L == 0) ? G0  : (L == 1) ? G1  : G2;
  unsigned rest = (unsigned)idx / (unsigned)GG;
  int cell = idx - (int)rest * GG;
  unsigned b = rest / 3u;
  int a = (int)(rest - b * 3u);
  int fbase = ((int)(b * 3u) + a) * 85 * GG + cell;
  float t0 = fp[fbase];
  float t1 = fp[fbase + GG];
  float t2 = fp[fbase + 2 * GG];
  float t3 = fp[fbase + 3 * GG];
  float t4 = fp[fbase + 4 * GG];
  unsigned yi = (unsigned)cell / (unsigned)G;
  int xi = cell - (int)yi * G;
  float inv_g = 1.0f / (float)G;
  float aw = d_anch[L][a][0], ah = d_anch[L][a][1];
  float px = (sigm(t0) + (float)xi) * inv_g;
  float py = (sigm(t1) + (float)yi) * inv_g;
  float pw = expf(t2) * aw * (1.0f / 416.0f);
  float ph = expf(t3) * ah * (1.0f / 416.0f);
  int si = L * BSZ + (int)b - gmin;
  int nb = scnt[si]; nb = nb > MAXB ? MAXB : nb;
  const float4* bx = sbox + si * MAXB;
  float pminx = px - pw * 0.5f, pmaxx = px + pw * 0.5f;
  float pminy = py - ph * 0.5f, pmaxy = py + ph * 0.5f;
  float pa = pw * ph;
  float best = 0.0f;
  for (int j = 0; j < nb; ++j) {
    float4 tb = bx[j];
    float iw = fminf(pmaxx, tb.x + tb.z * 0.5f) - fmaxf(pminx, tb.x - tb.z * 0.5f);
    float ih = fminf(pmaxy, tb.y + tb.w * 0.5f) - fmaxf(pminy, tb.y - tb.w * 0.5f);
    iw = fmaxf(iw, 0.f); ih = fmaxf(ih, 0.f);
    float inter = iw * ih;
    best = fmaxf(best, inter / (pa + tb.z * tb.w - inter));
  }
  return sp(t4) * (best < 0.5f ? 1.0f : 0.0f);   // obj treated as 0 here
}

__global__ __launch_bounds__(256)
void loss_kernel(const float* __restrict__ f0, const float* __restrict__ f1,
                 const float* __restrict__ f2, const float* __restrict__ y0,
                 const float* __restrict__ y1, const float* __restrict__ y2,
                 const int* __restrict__ cnt, const float* __restrict__ boxes,
                 const int* __restrict__ total, const int* __restrict__ objlist,
                 float* __restrict__ acc, int* __restrict__ done,
                 float* __restrict__ out) {
  __shared__ float4 sbox[2 * MAXB];
  __shared__ int scnt[2];
  float vxy = 0.f, vwh = 0.f, vconf = 0.f, vcls = 0.f;
  int lane = threadIdx.x & 63, wv = threadIdx.x >> 6;

  if (blockIdx.x < MB) {
    int tfirst = blockIdx.x * 256;
    int tlast  = min(tfirst + 255, TOTAL - 1);
    int gmin = cell_grp(tfirst);
    int ng = cell_grp(tlast) - gmin + 1;               // <= 2 (group span >= 507 cells)
    if (threadIdx.x < ng * MAXB)
      sbox[threadIdx.x] = ((const float4*)boxes)[gmin * MAXB + threadIdx.x];
    if (threadIdx.x < ng) scnt[threadIdx.x] = cnt[gmin + threadIdx.x];
    __syncthreads();
    int t = tfirst + threadIdx.x;
    if (t < TOTAL) {
      if (t < CELLS0)                vconf = conf_cell<0>(t,                   f0, sbox, scnt, gmin);
      else if (t < CELLS0 + CELLS1)  vconf = conf_cell<1>(t - CELLS0,          f1, sbox, scnt, gmin);
      else                           vconf = conf_cell<2>(t - CELLS0 - CELLS1, f2, sbox, scnt, gmin);
    }
  } else {
    // obj-correction path: one wave per obj cell (e is wave-uniform)
    int e = (blockIdx.x - MB) * 4 + wv;
    int tot = *total; if (tot > 1024) tot = 1024;
    if (e < tot) {
      int pk = objlist[e];
      int grp = pk >> 18, a = (pk >> 16) & 3, cell = pk & 0xFFFF;
      int l = grp >> 4, b = grp & 15;
      int GGv, Gv;
      const float *fp, *yp;
      if (l == 0)      { GGv = GG0; Gv = G0; fp = f0; yp = y0; }
      else if (l == 1) { GGv = GG1; Gv = G1; fp = f1; yp = y1; }
      else             { GGv = GG2; Gv = G2; fp = f2; yp = y2; }
      int rec   = b * GGv + cell;
      int ybase = rec * REC + a * 85;
      int fbase = (b * NA + a) * 85 * GGv + cell;
      float objv = yp[ybase + 4];                      // broadcast load (==1.0)

      // lane-parallel class BCE: lane c covers class c, lanes 0..15 also c+64
      float lg = fp[fbase + (5 + lane) * GGv];
      vcls = sp(lg) - lg * yp[ybase + 5 + lane];
      if (lane < 16) {
        int c2 = lane + 64;
        float lg2 = fp[fbase + (5 + c2) * GGv];
        vcls += sp(lg2) - lg2 * yp[ybase + 5 + c2];
      }
      vcls *= objv;

      // all lanes: broadcast feats scalars, redundant box math
      float t0 = fp[fbase];
      float t1 = fp[fbase + GGv];
      float t2 = fp[fbase + 2 * GGv];
      float t3 = fp[fbase + 3 * GGv];
      float t4 = fp[fbase + 4 * GGv];
      int yi = (l == 0) ? cell / G0 : (l == 1) ? cell / G1 : cell / G2;
      int xi = cell - yi * Gv;
      float aw = d_anch[l][a][0], ah = d_anch[l][a][1];
      float px = (sigm(t0) + (float)xi) / (float)Gv;
      float py = (sigm(t1) + (float)yi) / (float)Gv;
      float pw = expf(t2) * aw * (1.0f / 416.0f);
      float ph = expf(t3) * ah * (1.0f / 416.0f);
      int nb = cnt[grp]; nb = nb > MAXB ? MAXB : nb;
      float iou = 0.0f;
      if (lane < nb) {                                  // lane-parallel IoU
        float4 tb = ((const float4*)boxes)[grp * MAXB + lane];
        float iw = fminf(px + pw * 0.5f, tb.x + tb.z * 0.5f) - fmaxf(px - pw * 0.5f, tb.x - tb.z * 0.5f);
        float ih = fminf(py + ph * 0.5f, tb.y + tb.w * 0.5f) - fmaxf(py - ph * 0.5f, tb.y - tb.w * 0.5f);
        iw = fmaxf(iw, 0.f); ih = fmaxf(ih, 0.f);
        float inter = iw * ih;
        iou = inter / (pw * ph + tb.z * tb.w - inter);
      }
      float best = wmax(iou);
      if (lane == 0) {
        float ytx = yp[ybase], yty = yp[ybase + 1];
        float ytw = yp[ybase + 2], yth = yp[ybase + 3];
        float rtx = ytx * (float)Gv - (float)xi;
        float rty = yty * (float)Gv - (float)yi;
        float scale = 2.0f - ytw * yth;
        vxy = objv * scale * ((sp(t0) - t0 * rtx) + (sp(t1) - t1 * rty));
        float rtw = logf(ytw * 416.0f / aw);
        float rth = logf(yth * 416.0f / ah);
        vwh = objv * scale * ((t2 - rtw) * (t2 - rtw) + (t3 - rth) * (t3 - rth));
        // main pass added sp(t4)*ignore (obj=0 form); replace with true term
        float ign = best < 0.5f ? 1.0f : 0.0f;
        float spt4 = sp(t4);
        float bce4 = spt4 - t4 * objv;
        vconf = bce4 * (objv + (1.0f - objv) * ign) - spt4 * ign;
      }
    }
  }

  // block reduction: wave shuffle -> LDS -> 4 atomics per block
  __shared__ float sm[4][4];
  vxy = wred(vxy); vwh = wred(vwh); vconf = wred(vconf); vcls = wred(vcls);
  if (lane == 0) { sm[0][wv] = vxy; sm[1][wv] = vwh; sm[2][wv] = vconf; sm[3][wv] = vcls; }
  __syncthreads();
  if (threadIdx.x < 4) {
    float s = sm[threadIdx.x][0] + sm[threadIdx.x][1] + sm[threadIdx.x][2] + sm[threadIdx.x][3];
    atomicAdd(&acc[threadIdx.x], s);
  }
  __syncthreads();

  // last finishing block writes the outputs
  if (threadIdx.x == 0) {
    __threadfence();
    int d = atomicAdd(done, 1);
    if (d == (int)gridDim.x - 1) {
      float xy = atomicAdd(&acc[0], 0.0f) * (1.0f / BSZ);
      float wh = atomicAdd(&acc[1], 0.0f) * (1.0f / BSZ);
      float cf = atomicAdd(&acc[2], 0.0f) * (1.0f / BSZ);
      float cl = atomicAdd(&acc[3], 0.0f) * (1.0f / BSZ);
      out[0] = xy + wh + cf + cl;
      out[1] = xy; out[2] = wh; out[3] = cf; out[4] = cl;
    }
  }
}

extern "C" void kernel_launch(void* const* d_in, const int* in_sizes, int n_in,
                              void* d_out, int out_size, void* d_ws, size_t ws_size,
                              hipStream_t stream) {
  // setup_inputs() dict order: feats0, ytrue0, feats1, ytrue1, feats2, ytrue2
  const float* f0 = (const float*)d_in[0];
  const float* y0 = (const float*)d_in[1];
  const float* f1 = (const float*)d_in[2];
  const float* y1 = (const float*)d_in[3];
  const float* f2 = (const float*)d_in[4];
  const float* y2 = (const float*)d_in[5];

  float* acc     = (float*)d_ws;                       // 4 floats @ 0
  int*   cnt     = (int*)((char*)d_ws + 64);           // 48 ints
  int*   total   = (int*)((char*)d_ws + 256);          // 1 int
  int*   done    = (int*)((char*)d_ws + 260);          // 1 int
  int*   objlist = (int*)((char*)d_ws + 512);          // 1024 ints
  float* boxes   = (float*)((char*)d_ws + 8192);       // 48*32*4 floats

  hipMemsetAsync(d_ws, 0, 512, stream);                // acc+cnt+total+done

  gather_kernel<<<MB, 256, 0, stream>>>(y0, y1, y2, cnt, boxes, total, objlist);
  loss_kernel<<<MB + OB, 256, 0, stream>>>(f0, f1, f2, y0, y1, y2,
                                           cnt, boxes, total, objlist,
                                           acc, done, (float*)d_out);
}